// Round 17
// baseline (211.951 us; speedup 1.0000x reference)
//
#include <hip/hip_runtime.h>
#include <hip/hip_bf16.h>
#include <math.h>

#define N_NODES 100000
#define N_EDGES 1200000
#define E4 (N_EDGES / 4)                 // 300000 int4 groups
#define NB_L1 ((N_NODES + 255) / 256)    // 391
// deg binning
#define RANGE 12800
#define NRANGE 8
#define CHK 64
#define NB_DEG (NRANGE * CHK)            // 512
#define GPC ((E4 + CHK - 1) / CHK)       // 4688
// coarse bins (bin = dst >> 8)
#define NBIN 391
#define BINCAP 3584
#define NB_P1 512
#define GP1 ((E4 + NB_P1 - 1) / NB_P1)   // 586
// weight quant: q = w * sscale[src] * WQ  (w<=1, sscale<~0.1 -> q < 32767)
#define WQ (8.f * 32767.f)
#define GLX_T 512

// ---------------- helpers ----------------
__device__ __forceinline__ float disf(float d) {
    return (d > 0.f) ? rsqrtf(d) : 0.f;
}

// ---------------- deg via LDS-binned multi-pass ----------------
__global__ void degbin_kernel(const int4* __restrict__ src4, const float4* __restrict__ attr4,
                              float* __restrict__ partial) {
    __shared__ float ldeg[RANGE];
    int rb = blockIdx.x;
    int r = rb / CHK;
    int c = rb - r * CHK;
    int base = r * RANGE;
    for (int j = threadIdx.x; j < RANGE; j += blockDim.x) ldeg[j] = 0.f;
    __syncthreads();
    int g0 = c * GPC;
    int g1 = g0 + GPC; if (g1 > E4) g1 = E4;
    for (int g = g0 + threadIdx.x; g < g1; g += blockDim.x) {
        int4 s = src4[g];
        float4 a = attr4[g];
        unsigned o;
        o = (unsigned)(s.x - base); if (o < RANGE) atomicAdd(&ldeg[o], a.x);
        o = (unsigned)(s.y - base); if (o < RANGE) atomicAdd(&ldeg[o], a.y);
        o = (unsigned)(s.z - base); if (o < RANGE) atomicAdd(&ldeg[o], a.z);
        o = (unsigned)(s.w - base); if (o < RANGE) atomicAdd(&ldeg[o], a.w);
    }
    __syncthreads();
    float* dstp = partial + (size_t)rb * RANGE;
    for (int j = threadIdx.x; j < RANGE; j += blockDim.x) dstp[j] = ldeg[j];
}

__global__ void degred_kernel(const float* __restrict__ partial, float* __restrict__ deg) {
    int i = blockIdx.x * blockDim.x + threadIdx.x;
    if (i >= N_NODES) return;
    int r = i / RANGE;
    int j = i - r * RANGE;
    const float* p = partial + (size_t)r * CHK * RANGE + j;
    float s = 0.f;
#pragma unroll
    for (int c = 0; c < CHK; c++) s += p[(size_t)c * RANGE];
    deg[i] = s;
}

// ---------------- phase 1: coarse bin scatter (role A) + layer-1 int8 (role B) ----------------
// record: x = (src << 8) | (dst & 255), y = bits of w = attr*rsqrt(deg[src])
__global__ void p1l1_kernel(const int4* __restrict__ src4, const int4* __restrict__ dst4,
                            const float4* __restrict__ attr4, const float* __restrict__ deg,
                            const float* __restrict__ x, const float* __restrict__ w1,
                            const float* __restrict__ b1,
                            int* __restrict__ binCursor, uint2* __restrict__ binRegion,
                            signed char* __restrict__ h1q, float* __restrict__ sscale) {
    __shared__ int lhist[NBIN];
    __shared__ int lbase[NBIN];
    __shared__ int lcnt[NBIN];
    __shared__ float sw[20 * 32];
    __shared__ float sb[32];

    if (blockIdx.x < NB_P1) {
        int g0 = blockIdx.x * GP1;
        int g1 = g0 + GP1; if (g1 > E4) g1 = E4;
        for (int j = threadIdx.x; j < NBIN; j += blockDim.x) { lhist[j] = 0; lcnt[j] = 0; }
        __syncthreads();
        for (int g = g0 + threadIdx.x; g < g1; g += blockDim.x) {
            int4 d = dst4[g];
            atomicAdd(&lhist[d.x >> 8], 1);
            atomicAdd(&lhist[d.y >> 8], 1);
            atomicAdd(&lhist[d.z >> 8], 1);
            atomicAdd(&lhist[d.w >> 8], 1);
        }
        __syncthreads();
        for (int j = threadIdx.x; j < NBIN; j += blockDim.x)
            lbase[j] = (lhist[j] > 0) ? atomicAdd(&binCursor[j], lhist[j]) : 0;
        __syncthreads();
        for (int g = g0 + threadIdx.x; g < g1; g += blockDim.x) {
            int4 s = src4[g];
            int4 d = dst4[g];
            float4 a = attr4[g];
            {
                int bin = d.x >> 8;
                float w = a.x * disf(deg[s.x]);
                int pos = lbase[bin] + atomicAdd(&lcnt[bin], 1);
                if (pos < BINCAP)
                    binRegion[(size_t)bin * BINCAP + pos] =
                        make_uint2(((unsigned)s.x << 8) | (unsigned)(d.x & 255), __float_as_uint(w));
            }
            {
                int bin = d.y >> 8;
                float w = a.y * disf(deg[s.y]);
                int pos = lbase[bin] + atomicAdd(&lcnt[bin], 1);
                if (pos < BINCAP)
                    binRegion[(size_t)bin * BINCAP + pos] =
                        make_uint2(((unsigned)s.y << 8) | (unsigned)(d.y & 255), __float_as_uint(w));
            }
            {
                int bin = d.z >> 8;
                float w = a.z * disf(deg[s.z]);
                int pos = lbase[bin] + atomicAdd(&lcnt[bin], 1);
                if (pos < BINCAP)
                    binRegion[(size_t)bin * BINCAP + pos] =
                        make_uint2(((unsigned)s.z << 8) | (unsigned)(d.z & 255), __float_as_uint(w));
            }
            {
                int bin = d.w >> 8;
                float w = a.w * disf(deg[s.w]);
                int pos = lbase[bin] + atomicAdd(&lcnt[bin], 1);
                if (pos < BINCAP)
                    binRegion[(size_t)bin * BINCAP + pos] =
                        make_uint2(((unsigned)s.w << 8) | (unsigned)(d.w & 255), __float_as_uint(w));
            }
        }
    } else {
        // layer 1: leaky(x@W1+b1), per-node max-abs int8 quantization (floored scale)
        for (int t = threadIdx.x; t < 20 * 32; t += blockDim.x) sw[t] = w1[t];
        if (threadIdx.x < 32) sb[threadIdx.x] = b1[threadIdx.x];
        __syncthreads();
        int i = (blockIdx.x - NB_P1) * blockDim.x + threadIdx.x;
        if (i >= N_NODES) return;
        float xr[20];
#pragma unroll
        for (int k = 0; k < 20; k++) xr[k] = x[(size_t)i * 20 + k];
        float row[32];
        float rmax = 0.f;
#pragma unroll
        for (int j = 0; j < 32; j++) {
            float a = sb[j];
#pragma unroll
            for (int k = 0; k < 20; k++) a += xr[k] * sw[k * 32 + j];
            a = (a > 0.f) ? a : 0.01f * a;
            row[j] = a;
            rmax = fmaxf(rmax, fabsf(a));
        }
        float sc = fmaxf(rmax * (1.f / 127.f), 1e-4f);
        float inv = 1.f / sc;
        sscale[i] = sc;
#pragma unroll
        for (int j = 0; j < 32; j++) {
            h1q[(size_t)i * 32 + j] = (signed char)lrintf(row[j] * inv);
        }
    }
}

// ---------------- fused: bin records -> LDS int32 t1 accumulation -> dense l2 + l3-proj ----------------
__global__ void glx_kernel(const int* __restrict__ binCursor, const uint2* __restrict__ binRegion,
                           const float* __restrict__ deg, const float* __restrict__ sscale,
                           const signed char* __restrict__ h1q,
                           const float* __restrict__ w2, const float* __restrict__ b2,
                           const float* __restrict__ w3,
                           float2* __restrict__ z0, float2* __restrict__ z1) {
    __shared__ float s0[32 * 64];
    __shared__ float s1[32 * 64];
    __shared__ float sw3[256];
    __shared__ float sb[64];
    __shared__ int   t1acc[256][33];     // padded: bank = (dl + k) % 32
    __shared__ float hf[8][32];
    __shared__ float tf[8][32];
    int b = blockIdx.x, tid = threadIdx.x;

    for (int t = tid; t < 32 * 64; t += GLX_T) { s0[t] = w2[t]; s1[t] = w2[2048 + t]; }
    for (int t = tid; t < 256; t += GLX_T) sw3[t] = w3[t];
    if (tid < 64) sb[tid] = b2[tid];
    int* tz = &t1acc[0][0];
    for (int t = tid; t < 256 * 33; t += GLX_T) tz[t] = 0;
    __syncthreads();

    // gather: integer LDS accumulation (exact, order-independent)
    int cnt = binCursor[b]; if (cnt > BINCAP) cnt = BINCAP;
    const uint2* reg = binRegion + (size_t)b * BINCAP;
    for (int r = tid; r < cnt; r += GLX_T) {
        uint2 rec = reg[r];
        int src = (int)(rec.x >> 8);
        int dl  = (int)(rec.x & 255u);
        float w = __uint_as_float(rec.y);
        float ws = w * sscale[src] * WQ;
        int wq = (int)(ws + 0.5f);
        if (wq > 32767) wq = 32767;
        const int4* hp = reinterpret_cast<const int4*>(h1q + (size_t)src * 32);
        int4 A = hp[0];
        int4 B = hp[1];
        int* arow = t1acc[dl];
#define ACC4(d, base) \
        atomicAdd(&arow[(base)+0], __mul24(wq, (int)(signed char)((d)      ))); \
        atomicAdd(&arow[(base)+1], __mul24(wq, (int)(signed char)((d) >>  8))); \
        atomicAdd(&arow[(base)+2], __mul24(wq, (int)(signed char)((d) >> 16))); \
        atomicAdd(&arow[(base)+3], __mul24(wq, (int)(signed char)((d) >> 24)));
        ACC4(A.x, 0)  ACC4(A.y, 4)  ACC4(A.z, 8)  ACC4(A.w, 12)
        ACC4(B.x, 16) ACC4(B.y, 20) ACC4(B.z, 24) ACC4(B.w, 28)
#undef ACC4
    }
    __syncthreads();

    // dense: 32 batches x 8 nodes; wave (64 lanes) = one node's 64 output features
    int ns = tid >> 6;         // 0..7
    int f  = tid & 63;
    for (int bat = 0; bat < 32; ++bat) {
        if (tid < 256) {
            int nsS = tid >> 5, k = tid & 31;
            int dl = bat * 8 + nsS;
            int node = b * 256 + dl;
            if (node < N_NODES) {
                float sc = sscale[node];
                hf[nsS][k] = sc * (float)(signed char)h1q[(size_t)node * 32 + k];
                float dn = -disf(deg[node]) * (1.f / WQ);
                tf[nsS][k] = dn * (float)t1acc[dl][k];
            }
        }
        __syncthreads();
        int node = b * 256 + bat * 8 + ns;
        if (node < N_NODES) {
            float a = sb[f];
#pragma unroll 8
            for (int k = 0; k < 32; ++k)
                a += hf[ns][k] * s0[k * 64 + f] + tf[ns][k] * s1[k * 64 + f];
            float v = (a > 0.f) ? a : 0.01f * a;
            float z00 = v * sw3[f * 2 + 0];
            float z01 = v * sw3[f * 2 + 1];
            float z10 = v * sw3[128 + f * 2 + 0];
            float z11 = v * sw3[128 + f * 2 + 1];
#pragma unroll
            for (int m = 32; m > 0; m >>= 1) {
                z00 += __shfl_xor(z00, m);
                z01 += __shfl_xor(z01, m);
                z10 += __shfl_xor(z10, m);
                z11 += __shfl_xor(z11, m);
            }
            if (f == 0) {
                z0[node] = make_float2(z00, z01);
                z1[node] = make_float2(z10, z11);
            }
        }
        __syncthreads();
    }
}

// ---------------- fused: bin records -> LDS float z1-accumulation -> epilogue + bin softmax ----------------
__global__ void gaccx_kernel(const int* __restrict__ binCursor, const uint2* __restrict__ binRegion,
                             const float* __restrict__ deg,
                             const float2* __restrict__ z0, const float2* __restrict__ z1,
                             const float* __restrict__ b3, const float* __restrict__ gw,
                             const float* __restrict__ gb, float4* __restrict__ quads) {
    __shared__ float acc2[256][2];
    __shared__ float sm[512], ss[512], s0s[512], s1s[512];
    int b = blockIdx.x, tid = threadIdx.x;
    float* az = &acc2[0][0];
    for (int t = tid; t < 512; t += 512) az[t] = 0.f;
    __syncthreads();
    int cnt = binCursor[b]; if (cnt > BINCAP) cnt = BINCAP;
    const uint2* reg = binRegion + (size_t)b * BINCAP;
    for (int r = tid; r < cnt; r += 512) {
        uint2 rec = reg[r];
        int src = (int)(rec.x >> 8);
        int dl  = (int)(rec.x & 255u);
        float w = __uint_as_float(rec.y);
        float2 zv = z1[src];
        atomicAdd(&acc2[dl][0], w * zv.x);
        atomicAdd(&acc2[dl][1], w * zv.y);
    }
    __syncthreads();
    float m = -INFINITY, se = 0.f, a0 = 0.f, a1 = 0.f;
    if (tid < 256) {
        int node = b * 256 + tid;
        if (node < N_NODES) {
            float di = -disf(deg[node]);
            float2 zz = z0[node];
            float o0 = zz.x + di * acc2[tid][0] + b3[0];
            float o1 = zz.y + di * acc2[tid][1] + b3[1];
            m = o0 * gw[0] + o1 * gw[1] + gb[0];
            se = 1.f; a0 = o0; a1 = o1;
        }
    }
    sm[tid] = m; ss[tid] = se; s0s[tid] = a0; s1s[tid] = a1;
    __syncthreads();
    for (int s = 256; s > 0; s >>= 1) {
        if (tid < s) {
            float mb = sm[tid + s];
            if (mb != -INFINITY) {
                float ma = sm[tid];
                if (ma == -INFINITY) {
                    sm[tid] = mb; ss[tid] = ss[tid + s]; s0s[tid] = s0s[tid + s]; s1s[tid] = s1s[tid + s];
                } else if (mb <= ma) {
                    float c = __expf(mb - ma);
                    ss[tid] += ss[tid + s] * c;
                    s0s[tid] += s0s[tid + s] * c;
                    s1s[tid] += s1s[tid + s] * c;
                } else {
                    float c = __expf(ma - mb);
                    ss[tid] = ss[tid] * c + ss[tid + s];
                    s0s[tid] = s0s[tid] * c + s0s[tid + s];
                    s1s[tid] = s1s[tid] * c + s1s[tid + s];
                    sm[tid] = mb;
                }
            }
        }
        __syncthreads();
    }
    if (tid == 0) quads[b] = make_float4(sm[0], ss[0], s0s[0], s1s[0]);
}

// ---------------- final merge (NBIN quads) + pooled + log_softmax ----------------
__global__ void accB_kernel(const float4* __restrict__ quads, float* __restrict__ out) {
    __shared__ float sm[512], ss[512], s0[512], s1[512];
    int t = threadIdx.x;
    float m = -INFINITY, se = 0.f, a0 = 0.f, a1 = 0.f;
    if (t < NBIN) {
        float4 q = quads[t];
        m = q.x; se = q.y; a0 = q.z; a1 = q.w;
    }
    sm[t] = m; ss[t] = se; s0[t] = a0; s1[t] = a1;
    __syncthreads();
    for (int s = 256; s > 0; s >>= 1) {
        if (t < s) {
            float mb = sm[t + s];
            if (mb != -INFINITY) {
                float ma = sm[t];
                if (ma == -INFINITY) {
                    sm[t] = mb; ss[t] = ss[t + s]; s0[t] = s0[t + s]; s1[t] = s1[t + s];
                } else if (mb <= ma) {
                    float c = __expf(mb - ma);
                    ss[t] += ss[t + s] * c;
                    s0[t] += s0[t + s] * c;
                    s1[t] += s1[t + s] * c;
                } else {
                    float c = __expf(ma - mb);
                    ss[t] = ss[t] * c + ss[t + s];
                    s0[t] = s0[t] * c + s0[t + s];
                    s1[t] = s1[t] * c + s1[t + s];
                    sm[t] = mb;
                }
            }
        }
        __syncthreads();
    }
    if (t == 0) {
        float se0 = ss[0];
        float p0 = s0[0] / se0;
        float p1 = s1[0] / se0;
        float mm = fmaxf(p0, p1);
        float l = mm + logf(__expf(p0 - mm) + __expf(p1 - mm));
        out[0] = p0 - l;
        out[1] = p1 - l;
    }
}

extern "C" void kernel_launch(void* const* d_in, const int* in_sizes, int n_in,
                              void* d_out, int out_size, void* d_ws, size_t ws_size,
                              hipStream_t stream) {
    const float* x    = (const float*)d_in[0];
    const int*   ei   = (const int*)d_in[1];
    const float* attr = (const float*)d_in[2];
    const float* w1   = (const float*)d_in[3];
    const float* b1   = (const float*)d_in[4];
    const float* w2   = (const float*)d_in[5];
    const float* b2   = (const float*)d_in[6];
    const float* w3   = (const float*)d_in[7];
    const float* b3   = (const float*)d_in[8];
    const float* gw   = (const float*)d_in[9];
    const float* gb   = (const float*)d_in[10];
    float* out = (float*)d_out;

    const int4*   src4  = (const int4*)ei;
    const int4*   dst4  = (const int4*)(ei + N_EDGES);
    const float4* attr4 = (const float4*)attr;

    // workspace layout (float units)
    float* ws = (float*)d_ws;
    size_t off = 0;
    int*      binCursor = (int*)(ws + off); off += NBIN;
    float*    deg       = ws + off; off += N_NODES;
    float*    sscale    = ws + off; off += N_NODES;
    off = (off + 3) & ~(size_t)3;
    float*    partial   = ws + off; off += (size_t)NB_DEG * RANGE;
    uint2*    binRegion = (uint2*)(ws + off); off += (size_t)NBIN * BINCAP * 2;
    signed char* h1q    = (signed char*)(ws + off); off += (size_t)N_NODES * 8;  // 32 int8
    float2*   z0  = (float2*)(ws + off); off += (size_t)N_NODES * 2;
    float2*   z1  = (float2*)(ws + off); off += (size_t)N_NODES * 2;
    off = (off + 3) & ~(size_t)3;
    float4*   quads = (float4*)(ws + off); off += (size_t)NBIN * 4;

    const int B = 256;
    auto cdiv = [](long long a, long long b) { return (int)((a + b - 1) / b); };

    hipMemsetAsync(binCursor, 0, NBIN * sizeof(int), stream);

    // deg (LDS-binned, no global atomics)
    degbin_kernel<<<NB_DEG, B, 0, stream>>>(src4, attr4, partial);
    degred_kernel<<<cdiv(N_NODES, B), B, 0, stream>>>(partial, deg);

    // phase-1 coarse bin scatter + layer-1 int8 (role-fused)
    p1l1_kernel<<<NB_P1 + NB_L1, B, 0, stream>>>(src4, dst4, attr4, deg, x, w1, b1,
                                                 binCursor, binRegion, h1q, sscale);

    // fused: records -> LDS int t1 accumulation -> dense l2 + l3 projection
    glx_kernel<<<NBIN, GLX_T, 0, stream>>>(binCursor, binRegion, deg, sscale, h1q,
                                           w2, b2, w3, z0, z1);

    // fused: records -> LDS float z1 accumulation -> epilogue + bin softmax
    gaccx_kernel<<<NBIN, 512, 0, stream>>>(binCursor, binRegion, deg, z0, z1,
                                           b3, gw, gb, quads);

    // final merge + log_softmax
    accB_kernel<<<1, 512, 0, stream>>>(quads, out);
}